// Round 8
// baseline (126.619 us; speedup 1.0000x reference)
//
#include <hip/hip_runtime.h>

// SIREN forward, MFMA, round 8: all weight fragments hoisted to registers.
//
// Ladder: 1526 (f32 spill) -> 473 (MFMA chain) -> 326 (1KB-contiguous stores)
// -> 122.5 us (sc0 sc1 nt stores: L2 RFO eliminated; FETCH 733->~50 MB).
// HW lesson: gfx950 TCC read-fills missed store lines regardless of `nt` and
// full-line coverage; only system-scope (sc0 sc1) stores bypass the fill.
//
// This round: weights are batch-invariant, so stop re-reading 40 KB of MFMA
// A-fragments from LDS every batch (46 ds_read_b128 on the critical path at
// 2 waves/SIMD). Hoist all 40 fragments (160 VGPR) into registers once per
// wave, loaded straight from global (L2-cached). MFMA is now pure-register;
// LDS keeps only the output stage (32 KB) + tiny bias tables.

typedef _Float16 half8 __attribute__((ext_vector_type(8)));
typedef float f32x4 __attribute__((ext_vector_type(4)));

#define OMEGA 5.0f

__global__ __launch_bounds__(256, 2) void siren_mfma_kernel(
    const float* __restrict__ coords,
    const float* __restrict__ W0, const float* __restrict__ b0,
    const float* __restrict__ W1, const float* __restrict__ b1,
    const float* __restrict__ W2, const float* __restrict__ b2,
    const float* __restrict__ W3, const float* __restrict__ b3,
    const float* __restrict__ W4, const float* __restrict__ b4,
    float* __restrict__ out, int n)
{
    __shared__ float4 w0tab[64];                  // {5*W0[n][0], 5*W0[n][1], 5*b0[n], 0}
    __shared__ __align__(16) float btab[3][64];   // 5*b1..b3
    __shared__ __align__(16) float b4tab[128];    // 5*b4
    // Per-wave output slab: 16 points x 128 cols f32 (8 KB/wave, 32 KB).
    // float4-chunk XOR swizzle (chunk ^= row&7): 0 bank conflicts (r5 PMC).
    __shared__ float stage[4][16][128];

    const int tid  = threadIdx.x;
    const int lane = tid & 63;
    const int g    = lane >> 4;        // lane group 0..3
    const int w    = tid >> 6;         // wave in block

    if (tid < 64) {
        w0tab[tid] = make_float4(OMEGA * W0[2 * tid], OMEGA * W0[2 * tid + 1],
                                 OMEGA * b0[tid], 0.f);
        btab[0][tid] = OMEGA * b1[tid];
        btab[1][tid] = OMEGA * b2[tid];
        btab[2][tid] = OMEGA * b3[tid];
    }
    if (tid < 128) b4tab[tid] = OMEGA * b4[tid];
    __syncthreads();

    // ---- hoist all MFMA A-fragments into registers (batch-invariant) ----
    // Fragment convention (k-slot): k = 32b + 16*(e>>2) + 4*(lane>>4) + (e&3),
    // applied symmetrically to A and B -> result invariant to HW k-order.
    auto load_frag = [&](const float* __restrict__ W, int mt, int b) -> half8 {
        const float* src = W + (16 * mt + (lane & 15)) * 64 + 32 * b + 4 * g;
        float4 wa = *(const float4*)(src);
        float4 wb = *(const float4*)(src + 16);
        half8 h;
        h[0] = (_Float16)(OMEGA * wa.x); h[1] = (_Float16)(OMEGA * wa.y);
        h[2] = (_Float16)(OMEGA * wa.z); h[3] = (_Float16)(OMEGA * wa.w);
        h[4] = (_Float16)(OMEGA * wb.x); h[5] = (_Float16)(OMEGA * wb.y);
        h[6] = (_Float16)(OMEGA * wb.z); h[7] = (_Float16)(OMEGA * wb.w);
        return h;
    };

    half8 AH[3][2][4];   // hidden layers: 96 VGPR
    half8 A4[2][8];      // output layer:  64 VGPR
    {
        const float* Wp[3] = {W1, W2, W3};
        #pragma unroll
        for (int L = 0; L < 3; ++L)
            #pragma unroll
            for (int b = 0; b < 2; ++b)
                #pragma unroll
                for (int mt = 0; mt < 4; ++mt)
                    AH[L][b][mt] = load_frag(Wp[L], mt, b);
        #pragma unroll
        for (int b = 0; b < 2; ++b)
            #pragma unroll
            for (int mt = 0; mt < 8; ++mt)
                A4[b][mt] = load_frag(W4, mt, b);
    }

    // ---------------- main loop: one wave = 16 points per batch ----------------
    const int p   = lane & 15;                // point-in-batch (= MFMA column)
    const int sr  = lane >> 5;                // store-side row parity (0/1)
    const int sc  = lane & 31;                // store-side float4 chunk 0..31
    const int nb  = (n + 15) >> 4;
    const int wv  = blockIdx.x * 4 + w;
    const int nw  = gridDim.x * 4;

    for (int batch = wv; batch < nb; batch += nw) {
        int point = batch * 16 + p;
        int pt    = point < n ? point : n - 1;
        float2 c2 = *(const float2*)(coords + 2ull * (unsigned)pt);

        // Layer 0 (fp32 VALU): lane computes Z0[nrn][p] for nrn = 16t+4g+r,
        // landing directly in B-fragment slots: zb[t>>1][4*(t&1)+r].
        half8 zb[2];
        #pragma unroll
        for (int t = 0; t < 4; ++t) {
            #pragma unroll
            for (int r = 0; r < 4; ++r) {
                float4 ww = w0tab[16 * t + 4 * g + r];
                float z = __sinf(fmaf(c2.x, ww.x, fmaf(c2.y, ww.y, ww.z)));
                zb[t >> 1][4 * (t & 1) + r] = (_Float16)z;
            }
        }

        // Hidden layers 1..3: pure-register MFMA
        #pragma unroll
        for (int L = 0; L < 3; ++L) {
            f32x4 acc[4];
            #pragma unroll
            for (int t = 0; t < 4; ++t) {
                float4 bv = *(const float4*)&btab[L][16 * t + 4 * g];
                acc[t][0] = bv.x; acc[t][1] = bv.y; acc[t][2] = bv.z; acc[t][3] = bv.w;
            }
            #pragma unroll
            for (int b = 0; b < 2; ++b) {
                #pragma unroll
                for (int mt = 0; mt < 4; ++mt) {
                    acc[mt] = __builtin_amdgcn_mfma_f32_16x16x32_f16(
                        AH[L][b][mt], zb[b], acc[mt], 0, 0, 0);
                }
            }
            // activation + repack: D-regs -> next B-frags, all in-lane
            half8 zn[2];
            #pragma unroll
            for (int t = 0; t < 4; ++t) {
                #pragma unroll
                for (int r = 0; r < 4; ++r) {
                    zn[t >> 1][4 * (t & 1) + r] = (_Float16)__sinf(acc[t][r]);
                }
            }
            zb[0] = zn[0]; zb[1] = zn[1];
        }

        // Output layer: 64 -> 128, all 8 mt-tiles into the per-wave LDS slab
        // (chunk-XOR swizzle), then 8 fully-contiguous 1 KB bypass stores.
        #pragma unroll
        for (int mt = 0; mt < 8; ++mt) {
            float4 bv = *(const float4*)&b4tab[16 * mt + 4 * g];
            f32x4 a4;
            a4[0] = bv.x; a4[1] = bv.y; a4[2] = bv.z; a4[3] = bv.w;
            a4 = __builtin_amdgcn_mfma_f32_16x16x32_f16(A4[0][mt], zb[0], a4, 0, 0, 0);
            a4 = __builtin_amdgcn_mfma_f32_16x16x32_f16(A4[1][mt], zb[1], a4, 0, 0, 0);
            f32x4 o;
            o[0] = __sinf(a4[0]); o[1] = __sinf(a4[1]);
            o[2] = __sinf(a4[2]); o[3] = __sinf(a4[3]);
            int chunk = (4 * mt + g) ^ (p & 7);      // float4-chunk swizzle
            *(f32x4*)&stage[w][p][4 * chunk] = o;
        }
        // Store: instruction i writes point rows 2i (lanes 0-31) and 2i+1
        // (lanes 32-63) -- 1 KB contiguous per instruction.
        // sc0 sc1 nt: system-scope streaming store -> bypasses per-XCD L2,
        // no read-for-ownership fill (proved r7: FETCH 733 MB -> ~50 MB).
        const float* sbase = &stage[w][0][0];
        #pragma unroll
        for (int i = 0; i < 8; ++i) {
            int row = 2 * i + sr;
            int cs  = sc ^ (row & 7);
            f32x4 o4 = *(const f32x4*)(sbase + 128 * row + 4 * cs);
            int pointp = batch * 16 + row;
            if (pointp < n) {
                float* gp = out + (size_t)pointp * 128 + 4 * sc;
                asm volatile("global_store_dwordx4 %0, %1, off sc0 sc1 nt"
                             :: "v"(gp), "v"(o4) : "memory");
            }
        }
    }
}

extern "C" void kernel_launch(void* const* d_in, const int* in_sizes, int n_in,
                              void* d_out, int out_size, void* d_ws, size_t ws_size,
                              hipStream_t stream) {
    const float* coords = (const float*)d_in[0];
    const float* W0 = (const float*)d_in[1];
    const float* b0 = (const float*)d_in[2];
    const float* W1 = (const float*)d_in[3];
    const float* b1 = (const float*)d_in[4];
    const float* W2 = (const float*)d_in[5];
    const float* b2 = (const float*)d_in[6];
    const float* W3 = (const float*)d_in[7];
    const float* b3 = (const float*)d_in[8];
    const float* W4 = (const float*)d_in[9];
    const float* b4 = (const float*)d_in[10];
    float* out = (float*)d_out;

    int n = in_sizes[0] / 2;  // coords is (N, 2)
    int nb = (n + 15) / 16;
    int blocks = 512;         // 2 blocks/CU (VGPR-limited: 2 waves/SIMD)
    int maxb = (nb + 3) / 4;
    if (blocks > maxb) blocks = maxb;
    hipLaunchKernelGGL(siren_mfma_kernel, dim3(blocks), dim3(256), 0, stream,
                       coords, W0, b0, W1, b1, W2, b2, W3, b3, W4, b4, out, n);
}